// Round 5
// baseline (1143.777 us; speedup 1.0000x reference)
//
#include <hip/hip_runtime.h>
#include <hip/hip_fp16.h>
#include <stdint.h>

// B=512, S=512, F=64, H=128, 4H=512, O=64
#define SEQ 512
#define HID 128

typedef short bf16x8 __attribute__((ext_vector_type(8)));   // 8 bf16 = 4 VGPR
typedef float f32x4v __attribute__((ext_vector_type(4)));   // MFMA acc

#define MFMA16(a, b, c) __builtin_amdgcn_mfma_f32_16x16x32_bf16((a), (b), (c), 0, 0, 0)

__device__ __forceinline__ uint32_t bfr(float f) {          // fp32 -> bf16 (RNE)
    uint32_t u = __float_as_uint(f);
    return (u + 0x7fffu + ((u >> 16) & 1u)) >> 16;
}
__device__ __forceinline__ uint32_t bfp(float a, float b) { // pack 2 bf16
    return bfr(a) | (bfr(b) << 16);
}
__device__ __forceinline__ float fsig(float x) {
    return __builtin_amdgcn_rcpf(1.0f + __expf(-x));
}
__device__ __forceinline__ float ftanh(float x) {
    return 1.0f - 2.0f * __builtin_amdgcn_rcpf(__expf(2.0f * x) + 1.0f);
}
__device__ __forceinline__ uint32_t pkh2(float a, float b) { // pack 2 fp16
    union { __half h; uint16_t u; } ua, ub;
    ua.h = __float2half(a); ub.h = __float2half(b);
    return (uint32_t)ua.u | ((uint32_t)ub.u << 16);
}
__device__ __forceinline__ float2 uph2(uint32_t u) {        // unpack 2 fp16
    union { uint16_t u; __half h; } a, b;
    a.u = (uint16_t)(u & 0xffff); b.u = (uint16_t)(u >> 16);
    return make_float2(__half2float(a.h), __half2float(b.h));
}

// A-fragment: lane holds W[row][k0 .. k0+7] as bf16x8 (row = base + lane&15).
__device__ __forceinline__ bf16x8 afrag(const float* W, int row, int K, int k0) {
    const float4* p = (const float4*)(W + (size_t)row * K + k0);
    float4 a = p[0], b = p[1];
    union { bf16x8 v; uint32_t u[4]; } f;
    f.u[0] = bfp(a.x, a.y); f.u[1] = bfp(a.z, a.w);
    f.u[2] = bfp(b.x, b.y); f.u[3] = bfp(b.z, b.w);
    return f.v;
}

// float4-pair -> bf16 hi frag + bf16 residual(lo) frag
__device__ __forceinline__ void hilo(float4 a, float4 b, bf16x8* hi, bf16x8* lo) {
    float av[8] = {a.x, a.y, a.z, a.w, b.x, b.y, b.z, b.w};
    uint32_t hu[8]; float r[8];
#pragma unroll
    for (int i = 0; i < 8; i++) {
        hu[i] = bfr(av[i]);
        r[i] = av[i] - __uint_as_float(hu[i] << 16);
    }
    union { bf16x8 v; uint32_t u[4]; } H, L;
#pragma unroll
    for (int k = 0; k < 4; k++) {
        H.u[k] = hu[2 * k] | (hu[2 * k + 1] << 16);
        L.u[k] = bfp(r[2 * k], r[2 * k + 1]);
    }
    *hi = H.v; *lo = L.v;
}

// xp layout: uint2 (4 fp16, e=0..3) at idx = ((t*32+bblk)*128 + gq)*16 + b
//   where gq = grow>>2 (grow = gate row 0..511), b = batch-in-block 0..15.
// hseq granule layout (bf16): (((t*32+bblk)*16 + jblk)*16 + b)*8 + ji

// =============== xp0 = Wih0 @ x  (hi/lo split, fp16 out) ===============
__global__ __launch_bounds__(512, 2) void xp_gemm0(
    const float* __restrict__ x, const float* __restrict__ Wih, uint2* __restrict__ xp)
{
    const int tid = threadIdx.x, wid = tid >> 6, lane = tid & 63;
    const int l15 = lane & 15, lg = lane >> 4;
    const int bblk = blockIdx.x, bb = bblk * 16, tc = blockIdx.y, jb = wid * 16;

    bf16x8 w[4][2];
#pragma unroll
    for (int c = 0; c < 4; c++)
#pragma unroll
        for (int kt = 0; kt < 2; kt++)
            w[c][kt] = afrag(Wih, c * 128 + jb + l15, 64, kt * 32 + lg * 8);

    const float* xr = x + (size_t)(bb + l15) * SEQ * 64;
    for (int s = 0; s < 16; s++) {
        const int t = tc * 16 + s;
        const float4* p = (const float4*)(xr + (size_t)t * 64);
        float4 A1 = p[lg * 2], A2 = p[lg * 2 + 1];
        float4 B1 = p[8 + lg * 2], B2 = p[8 + lg * 2 + 1];
        bf16x8 xb[4];
        hilo(A1, A2, &xb[0], &xb[2]);
        hilo(B1, B2, &xb[1], &xb[3]);
        const int base = (t * 32 + bblk) * 128;
#pragma unroll
        for (int c = 0; c < 4; c++) {
            f32x4v a = MFMA16(w[c][0], xb[0], (f32x4v{0.f, 0.f, 0.f, 0.f}));
            a = MFMA16(w[c][1], xb[1], a);
            a = MFMA16(w[c][0], xb[2], a);
            a = MFMA16(w[c][1], xb[3], a);
            int idx = (base + 32 * c + 4 * wid + lg) * 16 + l15;
            xp[idx] = make_uint2(pkh2(a[0], a[1]), pkh2(a[2], a[3]));
        }
    }
}

// =============== xp1 = Wih1 @ h0  (h0 bf16 granules, fp16 out) ===============
__global__ __launch_bounds__(512, 2) void xp_gemm1(
    const unsigned short* __restrict__ hseq, const float* __restrict__ Wih,
    uint2* __restrict__ xp)
{
    const int tid = threadIdx.x, wid = tid >> 6, lane = tid & 63;
    const int l15 = lane & 15, lg = lane >> 4;
    const int bblk = blockIdx.x, tc = blockIdx.y, jb = wid * 16;

    bf16x8 w[4][4];
#pragma unroll
    for (int c = 0; c < 4; c++)
#pragma unroll
        for (int kt = 0; kt < 4; kt++)
            w[c][kt] = afrag(Wih, c * 128 + jb + l15, 128, kt * 32 + lg * 8);

    for (int s = 0; s < 16; s++) {
        const int t = tc * 16 + s;
        bf16x8 hf[4];
#pragma unroll
        for (int kt = 0; kt < 4; kt++) {
            int g = ((t * 32 + bblk) * 16 + kt * 4 + lg) * 16 + l15;
            hf[kt] = *(const bf16x8*)(hseq + (size_t)g * 8);
        }
        const int base = (t * 32 + bblk) * 128;
#pragma unroll
        for (int c = 0; c < 4; c++) {
            f32x4v a = MFMA16(w[c][0], hf[0], (f32x4v{0.f, 0.f, 0.f, 0.f}));
#pragma unroll
            for (int kt = 1; kt < 4; kt++) a = MFMA16(w[c][kt], hf[kt], a);
            int idx = (base + 32 * c + 4 * wid + lg) * 16 + l15;
            xp[idx] = make_uint2(pkh2(a[0], a[1]), pkh2(a[2], a[3]));
        }
    }
}

// =============== L0 recurrence: gates = xp0 + Whh0@h; writes hseq ===============
__global__ __launch_bounds__(512, 2) void lstm_rec0(
    const uint2* __restrict__ xp, const float* __restrict__ Whh,
    const float* __restrict__ bih, const float* __restrict__ bhh,
    unsigned short* __restrict__ hseq)
{
    const int tid = threadIdx.x, wid = tid >> 6, lane = tid & 63;
    const int l15 = lane & 15, lg = lane >> 4;
    const int bblk = blockIdx.x, jb = wid * 16;

    __shared__ __align__(16) uint8_t lds[8192];   // 2 x 4096 h dbuf (swizzled bf16)

    bf16x8 whh[4][4];
    f32x4v bias[4];
#pragma unroll
    for (int c = 0; c < 4; c++) {
#pragma unroll
        for (int kt = 0; kt < 4; kt++)
            whh[c][kt] = afrag(Whh, c * 128 + jb + l15, 128, kt * 32 + lg * 8);
#pragma unroll
        for (int e = 0; e < 4; e++) {
            int gr = c * 128 + jb + lg * 4 + e;
            bias[c][e] = bih[gr] + bhh[gr];
        }
    }

    *(f32x4v*)(lds + tid * 16) = f32x4v{0.f, 0.f, 0.f, 0.f};  // zero both parities

    int idxc[4];
#pragma unroll
    for (int c = 0; c < 4; c++) idxc[c] = (bblk * 128 + 32 * c + 4 * wid + lg) * 16 + l15;
    uint2 xpc[4], xpn[4];
#pragma unroll
    for (int c = 0; c < 4; c++) xpc[c] = xp[idxc[c]];
    __syncthreads();

    float cst[4] = {0.f, 0.f, 0.f, 0.f};
    const int j0 = jb + lg * 4;
    const int hwb = l15 * 256 + ((2 * j0) ^ ((l15 & 7) << 4));
    const int swz = (l15 & 7) << 4;

    for (int t = 0; t < SEQ; t++) {
        const uint8_t* hb = lds + (t & 1) * 4096;
        bf16x8 hf[4];
#pragma unroll
        for (int kt = 0; kt < 4; kt++) {
            int kb = (2 * (kt * 32 + lg * 8)) ^ swz;
            hf[kt] = *(const bf16x8*)(hb + l15 * 256 + kb);
        }
        if (t + 1 < SEQ) {
#pragma unroll
            for (int c = 0; c < 4; c++)
                xpn[c] = xp[(size_t)(t + 1) * 65536 + idxc[c]];
        }

        f32x4v acc[4];
#pragma unroll
        for (int c = 0; c < 4; c++) {
            f32x4v a = MFMA16(whh[c][0], hf[0], bias[c]);
#pragma unroll
            for (int kt = 1; kt < 4; kt++) a = MFMA16(whh[c][kt], hf[kt], a);
            acc[c] = a;
        }

        float2 xi01 = uph2(xpc[0].x), xi23 = uph2(xpc[0].y);
        float2 xf01 = uph2(xpc[1].x), xf23 = uph2(xpc[1].y);
        float2 xg01 = uph2(xpc[2].x), xg23 = uph2(xpc[2].y);
        float2 xo01 = uph2(xpc[3].x), xo23 = uph2(xpc[3].y);
        float xi[4] = {xi01.x, xi01.y, xi23.x, xi23.y};
        float xf[4] = {xf01.x, xf01.y, xf23.x, xf23.y};
        float xg[4] = {xg01.x, xg01.y, xg23.x, xg23.y};
        float xo[4] = {xo01.x, xo01.y, xo23.x, xo23.y};

        float h[4];
#pragma unroll
        for (int e = 0; e < 4; e++) {
            float ig = fsig(acc[0][e] + xi[e]);
            float fg = fsig(acc[1][e] + xf[e]);
            float gg = ftanh(acc[2][e] + xg[e]);
            float og = fsig(acc[3][e] + xo[e]);
            float cv = fg * cst[e] + ig * gg;
            cst[e] = cv;
            h[e] = og * ftanh(cv);
        }
        uint32_t hp0 = bfp(h[0], h[1]), hp1 = bfp(h[2], h[3]);
        *(uint2*)(lds + ((t + 1) & 1) * 4096 + hwb) = make_uint2(hp0, hp1);
        int gidx = (((t * 32 + bblk) * 16 + (j0 >> 3)) * 16 + l15) * 8 + (j0 & 7);
        *(uint2*)(hseq + gidx) = make_uint2(hp0, hp1);

        // raw barrier: wait LDS only; global store + xp loads stay in flight
        asm volatile("s_waitcnt lgkmcnt(0)\n\ts_barrier" ::: "memory");
#pragma unroll
        for (int c = 0; c < 4; c++) xpc[c] = xpn[c];
    }
}

// =============== L1 recurrence + FC ===============
__global__ __launch_bounds__(512, 2) void lstm_rec1fc(
    const uint2* __restrict__ xp, const float* __restrict__ Whh,
    const float* __restrict__ bih, const float* __restrict__ bhh,
    const float* __restrict__ fcw, const float* __restrict__ fcb,
    float* __restrict__ out)
{
    const int tid = threadIdx.x, wid = tid >> 6, lane = tid & 63;
    const int l15 = lane & 15, lg = lane >> 4;
    const int bblk = blockIdx.x, bb = bblk * 16, jb = wid * 16;

    __shared__ __align__(16) uint8_t lds[16384];  // 8K h dbuf + 8K f32 hfin
    float* hfin = (float*)(lds + 8192);

    bf16x8 whh[4][4];
    f32x4v bias[4];
#pragma unroll
    for (int c = 0; c < 4; c++) {
#pragma unroll
        for (int kt = 0; kt < 4; kt++)
            whh[c][kt] = afrag(Whh, c * 128 + jb + l15, 128, kt * 32 + lg * 8);
#pragma unroll
        for (int e = 0; e < 4; e++) {
            int gr = c * 128 + jb + lg * 4 + e;
            bias[c][e] = bih[gr] + bhh[gr];
        }
    }

    *(f32x4v*)(lds + tid * 16) = f32x4v{0.f, 0.f, 0.f, 0.f};

    int idxc[4];
#pragma unroll
    for (int c = 0; c < 4; c++) idxc[c] = (bblk * 128 + 32 * c + 4 * wid + lg) * 16 + l15;
    uint2 xpc[4], xpn[4];
#pragma unroll
    for (int c = 0; c < 4; c++) xpc[c] = xp[idxc[c]];
    __syncthreads();

    float cst[4] = {0.f, 0.f, 0.f, 0.f};
    const int j0 = jb + lg * 4;
    const int hwb = l15 * 256 + ((2 * j0) ^ ((l15 & 7) << 4));
    const int swz = (l15 & 7) << 4;

    for (int t = 0; t < SEQ; t++) {
        const uint8_t* hb = lds + (t & 1) * 4096;
        bf16x8 hf[4];
#pragma unroll
        for (int kt = 0; kt < 4; kt++) {
            int kb = (2 * (kt * 32 + lg * 8)) ^ swz;
            hf[kt] = *(const bf16x8*)(hb + l15 * 256 + kb);
        }
        if (t + 1 < SEQ) {
#pragma unroll
            for (int c = 0; c < 4; c++)
                xpn[c] = xp[(size_t)(t + 1) * 65536 + idxc[c]];
        }

        f32x4v acc[4];
#pragma unroll
        for (int c = 0; c < 4; c++) {
            f32x4v a = MFMA16(whh[c][0], hf[0], bias[c]);
#pragma unroll
            for (int kt = 1; kt < 4; kt++) a = MFMA16(whh[c][kt], hf[kt], a);
            acc[c] = a;
        }

        float2 xi01 = uph2(xpc[0].x), xi23 = uph2(xpc[0].y);
        float2 xf01 = uph2(xpc[1].x), xf23 = uph2(xpc[1].y);
        float2 xg01 = uph2(xpc[2].x), xg23 = uph2(xpc[2].y);
        float2 xo01 = uph2(xpc[3].x), xo23 = uph2(xpc[3].y);
        float xi[4] = {xi01.x, xi01.y, xi23.x, xi23.y};
        float xf[4] = {xf01.x, xf01.y, xf23.x, xf23.y};
        float xg[4] = {xg01.x, xg01.y, xg23.x, xg23.y};
        float xo[4] = {xo01.x, xo01.y, xo23.x, xo23.y};

        float h[4];
#pragma unroll
        for (int e = 0; e < 4; e++) {
            float ig = fsig(acc[0][e] + xi[e]);
            float fg = fsig(acc[1][e] + xf[e]);
            float gg = ftanh(acc[2][e] + xg[e]);
            float og = fsig(acc[3][e] + xo[e]);
            float cv = fg * cst[e] + ig * gg;
            cst[e] = cv;
            h[e] = og * ftanh(cv);
        }
        *(uint2*)(lds + ((t + 1) & 1) * 4096 + hwb) =
            make_uint2(bfp(h[0], h[1]), bfp(h[2], h[3]));
        if (t == SEQ - 1)
            *(f32x4v*)(hfin + l15 * HID + j0) = f32x4v{h[0], h[1], h[2], h[3]};

        asm volatile("s_waitcnt lgkmcnt(0)\n\ts_barrier" ::: "memory");
#pragma unroll
        for (int c = 0; c < 4; c++) xpc[c] = xpn[c];
    }
    __syncthreads();

    // fused FC: out[b][o] = relu(h1).fcw[o] + fcb[o]
    const int fb = tid >> 5, op = (tid & 31) * 2;
    float a0 = fcb[op], a1 = fcb[op + 1];
    const float4* w0 = (const float4*)(fcw + op * HID);
    const float4* w1 = (const float4*)(fcw + (op + 1) * HID);
    const float4* hv4 = (const float4*)(hfin + fb * HID);
#pragma unroll 8
    for (int k = 0; k < 32; k++) {
        float4 hv = hv4[k];
        float r0 = fmaxf(hv.x, 0.f), r1 = fmaxf(hv.y, 0.f);
        float r2 = fmaxf(hv.z, 0.f), r3 = fmaxf(hv.w, 0.f);
        float4 wa = w0[k], wb = w1[k];
        a0 += r0 * wa.x + r1 * wa.y + r2 * wa.z + r3 * wa.w;
        a1 += r0 * wb.x + r1 * wb.y + r2 * wb.z + r3 * wb.w;
    }
    out[(bb + fb) * 64 + op] = a0;
    out[(bb + fb) * 64 + op + 1] = a1;
}

// ====================== FALLBACK (R3 path, ws too small) ======================
__global__ __launch_bounds__(512, 2) void fb_l0(
    const float* __restrict__ x, const float* __restrict__ Wih,
    const float* __restrict__ Whh, const float* __restrict__ bih,
    const float* __restrict__ bhh, unsigned short* __restrict__ hseq)
{
    const int tid = threadIdx.x;
    const int wid = tid >> 6, lane = tid & 63;
    const int l15 = lane & 15, lg = lane >> 4;
    const int bblk = blockIdx.x, bb = bblk * 16;
    const int jb = wid * 16;

    __shared__ __align__(16) uint8_t lds[16384];
    uint8_t* hbuf = lds;
    uint8_t* xbuf = lds + 8192;

    bf16x8 wih[4][2], whh[4][4];
    f32x4v bias[4];
#pragma unroll
    for (int c = 0; c < 4; c++) {
        int row = c * 128 + jb + l15;
#pragma unroll
        for (int kt = 0; kt < 2; kt++) wih[c][kt] = afrag(Wih, row, 64, kt * 32 + lg * 8);
#pragma unroll
        for (int kt = 0; kt < 4; kt++) whh[c][kt] = afrag(Whh, row, 128, kt * 32 + lg * 8);
#pragma unroll
        for (int e = 0; e < 4; e++) {
            int gr = c * 128 + jb + lg * 4 + e;
            bias[c][e] = bih[gr] + bhh[gr];
        }
    }

    *(f32x4v*)(lds + tid * 16) = f32x4v{0.f, 0.f, 0.f, 0.f};
    const int xrb = tid >> 5, xf0 = (tid & 31) * 2;
    const size_t xbase = (size_t)(bb + xrb) * SEQ * 64 + xf0;
    {
        float2 v = *(const float2*)(x + xbase);
        uint32_t hx = bfr(v.x), hy = bfr(v.y);
        float rx = v.x - __uint_as_float(hx << 16);
        float ry = v.y - __uint_as_float(hy << 16);
        int kb = (2 * xf0) ^ ((xrb & 7) << 4);
        *(uint32_t*)(xbuf + xrb * 128 + kb) = hx | (hy << 16);
        *(uint32_t*)(xbuf + 2048 + xrb * 128 + kb) = bfr(rx) | (bfr(ry) << 16);
    }
    __syncthreads();

    float cst[4] = {0.f, 0.f, 0.f, 0.f};
    const int j0 = jb + lg * 4;
    const int hwb = l15 * 256 + ((2 * j0) ^ ((l15 & 7) << 4));
    const int swz = (l15 & 7) << 4;

    for (int t = 0; t < SEQ; t++) {
        float2 xv = {0.f, 0.f};
        if (t + 1 < SEQ) xv = *(const float2*)(x + xbase + (size_t)(t + 1) * 64);

        const uint8_t* hb = hbuf + (t & 1) * 4096;
        const uint8_t* xh = xbuf + (t & 1) * 4096;
        bf16x8 xhf[2], xlf[2], hf[4];
#pragma unroll
        for (int kt = 0; kt < 2; kt++) {
            int kb = (2 * (kt * 32 + lg * 8)) ^ swz;
            xhf[kt] = *(const bf16x8*)(xh + l15 * 128 + kb);
            xlf[kt] = *(const bf16x8*)(xh + 2048 + l15 * 128 + kb);
        }
#pragma unroll
        for (int kt = 0; kt < 4; kt++) {
            int kb = (2 * (kt * 32 + lg * 8)) ^ swz;
            hf[kt] = *(const bf16x8*)(hb + l15 * 256 + kb);
        }

        f32x4v acc[4];
#pragma unroll
        for (int c = 0; c < 4; c++) {
            f32x4v a = MFMA16(wih[c][0], xhf[0], bias[c]);
            a = MFMA16(wih[c][1], xhf[1], a);
            a = MFMA16(wih[c][0], xlf[0], a);
            a = MFMA16(wih[c][1], xlf[1], a);
#pragma unroll
            for (int kt = 0; kt < 4; kt++) a = MFMA16(whh[c][kt], hf[kt], a);
            acc[c] = a;
        }

        float h[4];
#pragma unroll
        for (int e = 0; e < 4; e++) {
            float ig = fsig(acc[0][e]);
            float fg = fsig(acc[1][e]);
            float gg = ftanh(acc[2][e]);
            float og = fsig(acc[3][e]);
            float cv = fg * cst[e] + ig * gg;
            cst[e] = cv;
            h[e] = og * ftanh(cv);
        }
        uint32_t hp0 = bfp(h[0], h[1]), hp1 = bfp(h[2], h[3]);

        if (t + 1 < SEQ) {
            uint8_t* xn = xbuf + ((t + 1) & 1) * 4096;
            uint32_t hx = bfr(xv.x), hy = bfr(xv.y);
            float rx = xv.x - __uint_as_float(hx << 16);
            float ry = xv.y - __uint_as_float(hy << 16);
            int kb = (2 * xf0) ^ ((xrb & 7) << 4);
            *(uint32_t*)(xn + xrb * 128 + kb) = hx | (hy << 16);
            *(uint32_t*)(xn + 2048 + xrb * 128 + kb) = bfr(rx) | (bfr(ry) << 16);
        }

        *(uint2*)(hbuf + ((t + 1) & 1) * 4096 + hwb) = make_uint2(hp0, hp1);
        {
            int gidx = (((t * 32 + bblk) * 16 + (j0 >> 3)) * 16 + l15) * 8 + (j0 & 7);
            *(uint2*)(hseq + gidx) = make_uint2(hp0, hp1);
        }
        __syncthreads();
    }
}

__global__ __launch_bounds__(512, 2) void fb_l1fc(
    const unsigned short* __restrict__ hseq, const float* __restrict__ Wih,
    const float* __restrict__ Whh, const float* __restrict__ bih,
    const float* __restrict__ bhh, const float* __restrict__ fcw,
    const float* __restrict__ fcb, float* __restrict__ out)
{
    const int tid = threadIdx.x;
    const int wid = tid >> 6, lane = tid & 63;
    const int l15 = lane & 15, lg = lane >> 4;
    const int bblk = blockIdx.x, bb = bblk * 16;
    const int jb = wid * 16;

    __shared__ __align__(16) uint8_t lds[16384];
    uint8_t* h1b = lds;
    float* hfin = (float*)(lds + 8192);

    bf16x8 wih[4][4], whh[4][4];
    f32x4v bias[4];
#pragma unroll
    for (int c = 0; c < 4; c++) {
        int row = c * 128 + jb + l15;
#pragma unroll
        for (int kt = 0; kt < 4; kt++) {
            wih[c][kt] = afrag(Wih, row, 128, kt * 32 + lg * 8);
            whh[c][kt] = afrag(Whh, row, 128, kt * 32 + lg * 8);
        }
#pragma unroll
        for (int e = 0; e < 4; e++) {
            int gr = c * 128 + jb + lg * 4 + e;
            bias[c][e] = bih[gr] + bhh[gr];
        }
    }

    *(f32x4v*)(lds + tid * 16) = f32x4v{0.f, 0.f, 0.f, 0.f};
    __syncthreads();

    float cst[4] = {0.f, 0.f, 0.f, 0.f};
    const int j0 = jb + lg * 4;
    const int hwb = l15 * 256 + ((2 * j0) ^ ((l15 & 7) << 4));
    const int swz = (l15 & 7) << 4;

    bf16x8 h0f[2][4];
#pragma unroll
    for (int kt = 0; kt < 4; kt++) {
        int g = ((0 * 32 + bblk) * 16 + (kt * 4 + lg)) * 16 + l15;
        h0f[0][kt] = *(const bf16x8*)(hseq + g * 8);
    }

    for (int tp = 0; tp < SEQ / 2; tp++) {
#pragma unroll
        for (int ph = 0; ph < 2; ph++) {
            const int t = 2 * tp + ph;
            if (t + 1 < SEQ) {
#pragma unroll
                for (int kt = 0; kt < 4; kt++) {
                    int g = (((t + 1) * 32 + bblk) * 16 + (kt * 4 + lg)) * 16 + l15;
                    h0f[ph ^ 1][kt] = *(const bf16x8*)(hseq + g * 8);
                }
            }
            const uint8_t* hb = h1b + (t & 1) * 4096;
            bf16x8 h1f[4];
#pragma unroll
            for (int kt = 0; kt < 4; kt++) {
                int kb = (2 * (kt * 32 + lg * 8)) ^ swz;
                h1f[kt] = *(const bf16x8*)(hb + l15 * 256 + kb);
            }

            f32x4v acc[4];
#pragma unroll
            for (int c = 0; c < 4; c++) {
                f32x4v a = MFMA16(wih[c][0], h0f[ph][0], bias[c]);
#pragma unroll
                for (int kt = 1; kt < 4; kt++) a = MFMA16(wih[c][kt], h0f[ph][kt], a);
#pragma unroll
                for (int kt = 0; kt < 4; kt++) a = MFMA16(whh[c][kt], h1f[kt], a);
                acc[c] = a;
            }

            float h[4];
#pragma unroll
            for (int e = 0; e < 4; e++) {
                float ig = fsig(acc[0][e]);
                float fg = fsig(acc[1][e]);
                float gg = ftanh(acc[2][e]);
                float og = fsig(acc[3][e]);
                float cv = fg * cst[e] + ig * gg;
                cst[e] = cv;
                h[e] = og * ftanh(cv);
            }
            *(uint2*)(h1b + ((t + 1) & 1) * 4096 + hwb) = make_uint2(bfp(h[0], h[1]), bfp(h[2], h[3]));
            if (t == SEQ - 1)
                *(f32x4v*)(hfin + l15 * HID + j0) = f32x4v{h[0], h[1], h[2], h[3]};
            __syncthreads();
        }
    }

    const int fb = tid >> 5, op = (tid & 31) * 2;
    float a0 = fcb[op], a1 = fcb[op + 1];
    const float4* w0 = (const float4*)(fcw + op * HID);
    const float4* w1 = (const float4*)(fcw + (op + 1) * HID);
    const float4* hv4 = (const float4*)(hfin + fb * HID);
#pragma unroll 8
    for (int k = 0; k < 32; k++) {
        float4 hv = hv4[k];
        float r0 = fmaxf(hv.x, 0.f), r1 = fmaxf(hv.y, 0.f);
        float r2 = fmaxf(hv.z, 0.f), r3 = fmaxf(hv.w, 0.f);
        float4 wa = w0[k], wb = w1[k];
        a0 += r0 * wa.x + r1 * wa.y + r2 * wa.z + r3 * wa.w;
        a1 += r0 * wb.x + r1 * wb.y + r2 * wb.z + r3 * wb.w;
    }
    out[(bb + fb) * 64 + op] = a0;
    out[(bb + fb) * 64 + op + 1] = a1;
}

extern "C" void kernel_launch(void* const* d_in, const int* in_sizes, int n_in,
                              void* d_out, int out_size, void* d_ws, size_t ws_size,
                              hipStream_t stream) {
    const float* x    = (const float*)d_in[0];
    const float* Wih0 = (const float*)d_in[1];
    const float* Whh0 = (const float*)d_in[2];
    const float* bih0 = (const float*)d_in[3];
    const float* bhh0 = (const float*)d_in[4];
    const float* Wih1 = (const float*)d_in[5];
    const float* Whh1 = (const float*)d_in[6];
    const float* bih1 = (const float*)d_in[7];
    const float* bhh1 = (const float*)d_in[8];
    const float* fcw  = (const float*)d_in[9];
    const float* fcb  = (const float*)d_in[10];

    const size_t XP_BYTES = 268435456;   // [S][32][128 gq][16 b] uint2 fp16x4
    const size_t HS_BYTES = 67108864;    // hseq bf16 granules

    if (ws_size >= XP_BYTES + HS_BYTES) {
        uint2* xp = (uint2*)d_ws;
        unsigned short* hseq = (unsigned short*)((char*)d_ws + XP_BYTES);
        xp_gemm0<<<dim3(32, 32), 512, 0, stream>>>(x, Wih0, xp);
        lstm_rec0<<<32, 512, 0, stream>>>(xp, Whh0, bih0, bhh0, hseq);
        xp_gemm1<<<dim3(32, 32), 512, 0, stream>>>(hseq, Wih1, xp);
        lstm_rec1fc<<<32, 512, 0, stream>>>(xp, Whh1, bih1, bhh1, fcw, fcb, (float*)d_out);
    } else {
        unsigned short* hseq = (unsigned short*)d_ws;
        fb_l0<<<32, 512, 0, stream>>>(x, Wih0, Whh0, bih0, bhh0, hseq);
        fb_l1fc<<<32, 512, 0, stream>>>(hseq, Wih1, Whh1, bih1, bhh1, fcw, fcb, (float*)d_out);
    }
}